// Round 11
// baseline (46.585 us; speedup 1.0000x reference)
//
#include <hip/hip_runtime.h>

typedef _Float16 half2v __attribute__((ext_vector_type(2)));
typedef _Float16 half8v __attribute__((ext_vector_type(8)));
typedef float f32x4 __attribute__((ext_vector_type(4)));
typedef unsigned uint2v __attribute__((ext_vector_type(2)));
typedef unsigned uint4v __attribute__((ext_vector_type(4)));

__device__ inline half2v cvt_pk(float a, float b) {
    return __builtin_bit_cast(half2v, __builtin_amdgcn_cvt_pkrtz(a, b));
}
__device__ inline half2v pkmax0(half2v x) {
    half2v r;
    asm("v_pk_max_f16 %0, %1, 0" : "=v"(r) : "v"(x));
    return r;
}
__device__ inline unsigned short f16bits(float f) {
    _Float16 h = (_Float16)f;
    return __builtin_bit_cast(unsigned short, h);
}
__device__ inline unsigned packf16(float a, float b) {
    return (unsigned)f16bits(a) | ((unsigned)f16bits(b) << 16);
}
__device__ inline float lo16(unsigned u) {
    return (float)__builtin_bit_cast(_Float16, (unsigned short)(u & 0xffffu));
}
__device__ inline float hi16(unsigned u) {
    return (float)__builtin_bit_cast(_Float16, (unsigned short)(u >> 16));
}
// MFMA with the A-operand (weight) forced into the AGPR class: the VGPR
// allocator has spilled 128 weight VGPRs to scratch for 3 rounds straight
// (R7 PIN / R9 LDS-demote / R10 LDS-overwrite all -> VGPR~100 + scratch
// remat = 42us). AGPRs are a separate allocation class on gfx950's unified
// file; defined-once weight values used only as "a" operands stay resident.
__device__ inline void mfma_aw(f32x4& c, half8v a, half8v b) {
    uint4v ai = __builtin_bit_cast(uint4v, a);
    uint4v bi = __builtin_bit_cast(uint4v, b);
    asm("v_mfma_f32_16x16x32_f16 %0, %1, %2, %0"
        : "+v"(c) : "a"(ai), "v"(bi));
}

// ---------------------------------------------------------------------------
// K0: src/dst = relu(LN(node @ W^T + b)) -> f16; A1 = src@W1a^T + b1 (f32);
//     B1h = dst@W1b^T (f16). W and the w1 k-slice staged in LDS as f16 with
//     conflict-free strides. Blocks 0..7 pack w1c/w2 into MFMA A-frag order
//     (w2 with sigma perm).
//       sigma(kt, lq*8+e) = (2*kt + (e>>2))*16 + lq*4 + (e&3)
// ---------------------------------------------------------------------------
__global__ __launch_bounds__(256) void proj_kernel(
    const float* __restrict__ node,
    const float* __restrict__ w_src, const float* __restrict__ b_src,
    const float* __restrict__ g_src, const float* __restrict__ be_src,
    const float* __restrict__ w_dst, const float* __restrict__ b_dst,
    const float* __restrict__ g_dst, const float* __restrict__ be_dst,
    const float* __restrict__ w1, const float* __restrict__ b1,
    const float* __restrict__ w2,
    unsigned short* __restrict__ src_f16, unsigned short* __restrict__ dst_f16,
    float* __restrict__ A1, unsigned short* __restrict__ B1h,
    unsigned short* __restrict__ w1c_frag, unsigned short* __restrict__ w2_frag)
{
    __shared__ unsigned sWh[64 * 65];    // W(kind) as packed f16 pairs, stride 65
    __shared__ unsigned sw1h[128 * 33];  // w1[:,koff:koff+64] f16 pairs, stride 33
    __shared__ float snode[4][128];
    __shared__ float sy[4][64];

    const int tid = threadIdx.x;
    const int wloc = tid >> 6;
    const int lane = tid & 63;
    const int gw = blockIdx.x * 4 + wloc;     // 0..2047
    const int row = gw & 1023;
    const int kind = gw >> 10;                // uniform per block

    const float* W  = kind ? w_dst  : w_src;
    const float* Bv = kind ? b_dst  : b_src;
    const float* G  = kind ? g_dst  : g_src;
    const float* BE = kind ? be_dst : be_src;
    const int koff = kind * 64;

    // ---- stage W (64x128) and w1-slice (128x64) as f16 pairs, coalesced ----
    #pragma unroll
    for (int u = 0; u < 16; u++) {
        int w = u * 256 + tid;                // 0..4095
        int r = w >> 6, c2 = w & 63;
        float2 v = *(const float2*)(W + r * 128 + c2 * 2);
        sWh[r * 65 + c2] = packf16(v.x, v.y);
    }
    #pragma unroll
    for (int u = 0; u < 16; u++) {
        int w = u * 256 + tid;                // 0..4095
        int r = w >> 5, c2 = w & 31;
        float2 v = *(const float2*)(w1 + (size_t)r * 192 + koff + c2 * 2);
        sw1h[r * 33 + c2] = packf16(v.x, v.y);
    }
    snode[wloc][lane]      = node[row * 128 + lane];
    snode[wloc][lane + 64] = node[row * 128 + 64 + lane];
    __syncthreads();

    // ---- projection dot: acc = b + node . W[lane,:] ----
    float acc = Bv[lane];
    #pragma unroll 8
    for (int k2 = 0; k2 < 64; k2++) {
        unsigned wp = sWh[lane * 65 + k2];
        float2 nv = *(const float2*)&snode[wloc][2 * k2];
        acc += nv.x * lo16(wp) + nv.y * hi16(wp);
    }

    // LayerNorm over 64 lanes
    float s = acc;
    #pragma unroll
    for (int off = 32; off >= 1; off >>= 1) s += __shfl_xor(s, off);
    float mean = s * (1.0f / 64.0f);
    float d = acc - mean;
    float ss = d * d;
    #pragma unroll
    for (int off = 32; off >= 1; off >>= 1) ss += __shfl_xor(ss, off);
    float rstd = rsqrtf(ss * (1.0f / 64.0f) + 1e-5f);
    float y = fmaxf(d * rstd * G[lane] + BE[lane], 0.0f);

    unsigned short* obf = kind ? dst_f16 : src_f16;
    obf[row * 64 + lane] = f16bits(y);

    sy[wloc][lane] = y;
    __builtin_amdgcn_s_waitcnt(0);   // within-wave LDS RAW

    // ---- A1/B1 projection: a{0,1} = y . w1[m, koff:koff+64] ----
    float a0 = kind ? 0.0f : b1[lane];
    float a1 = kind ? 0.0f : b1[lane + 64];
    #pragma unroll 8
    for (int k2 = 0; k2 < 32; k2++) {
        float2 yv = *(const float2*)&sy[wloc][2 * k2];
        unsigned wa = sw1h[lane * 33 + k2];
        unsigned wb = sw1h[(lane + 64) * 33 + k2];
        a0 += yv.x * lo16(wa) + yv.y * hi16(wa);
        a1 += yv.x * lo16(wb) + yv.y * hi16(wb);
    }
    if (kind == 0) {
        A1[row * 128 + lane] = a0;
        A1[row * 128 + lane + 64] = a1;
    } else {
        B1h[row * 128 + lane] = f16bits(a0);
        B1h[row * 128 + lane + 64] = f16bits(a1);
    }

    // ---- weight packing (blocks 0..7 only) ----
    if (blockIdx.x < 8) {
        int t = blockIdx.x * 256 + threadIdx.x;   // 0..2047
        int which = t >> 10;
        int idx = t & 1023;                       // f*64 + l
        int f = idx >> 6, l = idx & 63;
        int lqq = l >> 4, lrr = l & 15;
        if (which == 0) {
            int mt = f >> 1, kt = f & 1;          // A-frag of W1c
            #pragma unroll
            for (int e = 0; e < 8; e++)
                w1c_frag[idx * 8 + e] =
                    f16bits(w1[(size_t)(mt * 16 + lrr) * 192 + 128 + kt * 32 + lqq * 8 + e]);
        } else {
            int mt2 = f >> 2, kt2 = f & 3;        // A-frag of W2 with sigma perm
            #pragma unroll
            for (int e = 0; e < 8; e++) {
                int col = (2 * kt2 + (e >> 2)) * 16 + lqq * 4 + (e & 3);
                w2_frag[idx * 8 + e] =
                    f16bits(w2[(size_t)(mt2 * 16 + lrr) * 128 + col]);
            }
        }
    }
}

// ---------------------------------------------------------------------------
// K1: pairwise MLP. Weight fragments live in AGPRs (asm MFMA, "a" operand);
// cheap operands in LDS: sA1 (C-init), sSrc, sB1, sB2, sW3.
// Block = 32 i x 32 j, 4 waves; wave (wv&1, wv>>1) owns 16 i x 16 j.
// Chunk = (one i, 16 j = lr): GEMM1(C=A1) -> epi(+B1,relu,pack P) ->
// GEMM2(sigma-W2, own-reg B, C=b2 from LDS) -> VALU dot w3 -> shfl -> store.
// ---------------------------------------------------------------------------
__global__ __launch_bounds__(256, 2) void pair_kernel(
    const unsigned short* __restrict__ src_f16, const unsigned short* __restrict__ dst_f16,
    const float* __restrict__ A1, const unsigned short* __restrict__ B1h,
    const unsigned short* __restrict__ w1c_frag, const unsigned short* __restrict__ w2_frag,
    const float* __restrict__ b2, const float* __restrict__ w3,
    const float* __restrict__ b3, float* __restrict__ out)
{
    __shared__ __align__(16) float sA1[32][128];           // 16 KB
    __shared__ __align__(16) unsigned short sSrc[32][64];  // 4 KB
    __shared__ __align__(16) unsigned short sB1[32][136];  // 8.5 KB
    __shared__ __align__(16) float sB2[128];               // 0.5 KB
    __shared__ __align__(16) float sW3[64];                // 0.25 KB

    const int tid = threadIdx.x;
    const int wv = tid >> 6;
    const int lane = tid & 63;
    const int lq = lane >> 4, lr = lane & 15;
    const int i0 = blockIdx.y * 32, j0 = blockIdx.x * 32;
    const int ibase = (wv & 1) * 16;
    const int jl_base = (wv >> 1) * 16;
    const int jbase = j0 + jl_base;

    // ---- cooperative staging (coalesced) ----
    #pragma unroll
    for (int u = 0; u < 4; u++) {
        int idx = u * 256 + tid;              // 0..1023
        int r = idx >> 5, c = (idx & 31) * 4;
        *(f32x4*)&sA1[r][c] = *(const f32x4*)(A1 + (size_t)(i0 + r) * 128 + c);
    }
    {
        int r = tid >> 3, c = (tid & 7) * 8;
        *(uint4*)&sSrc[r][c] = *(const uint4*)(src_f16 + (size_t)(i0 + r) * 64 + c);
    }
    #pragma unroll
    for (int u = 0; u < 2; u++) {
        int idx = u * 256 + tid;              // 0..511
        int r = idx >> 4, c = (idx & 15) * 8;
        *(uint4*)&sB1[r][c] = *(const uint4*)(B1h + (size_t)(j0 + r) * 128 + c);
    }
    if (tid < 32) *(f32x4*)&sB2[tid * 4] = *(const f32x4*)(b2 + tid * 4);
    else if (tid < 48) *(f32x4*)&sW3[(tid - 32) * 4] = *(const f32x4*)(w3 + (tid - 32) * 4);

    // ---- weight fragments from global (coalesced b128, L2-hot) ----
    half8v w1f[8][2], w2f[4][4];
    {
        const uint4* gw1 = (const uint4*)w1c_frag;
        #pragma unroll
        for (int mt = 0; mt < 8; mt++)
            #pragma unroll
            for (int kt = 0; kt < 2; kt++)
                w1f[mt][kt] = __builtin_bit_cast(half8v, gw1[(mt * 2 + kt) * 64 + lane]);
        const uint4* gw2 = (const uint4*)w2_frag;
        #pragma unroll
        for (int mt2 = 0; mt2 < 4; mt2++)
            #pragma unroll
            for (int kt = 0; kt < 4; kt++)
                w2f[mt2][kt] = __builtin_bit_cast(half8v, gw2[(mt2 * 4 + kt) * 64 + lane]);
    }
    const float b3s = b3[0];

    // ---- j-side dst fragments: loaded once per wave ----
    const int j = jbase + lr;
    half8v dstf0, dstf1;
    {
        const uint4* drow = (const uint4*)(dst_f16 + (size_t)j * 64);
        dstf0 = __builtin_bit_cast(half8v, drow[lq]);
        dstf1 = __builtin_bit_cast(half8v, drow[4 + lq]);
    }
    const int jl = jl_base + lr;                 // row in sB1

    __syncthreads();

    // ---- 16 chunks: one i each; operands from LDS ----
    for (int cc = 0; cc < 16; cc++) {
        const int i_loc = ibase + cc;
        const int i = i0 + i_loc;
        const half8v s0 = *(const half8v*)&sSrc[i_loc][lq * 8];
        const half8v s1 = *(const half8v*)&sSrc[i_loc][32 + lq * 8];
        f32x4 acc1[8];
        #pragma unroll
        for (int mt = 0; mt < 8; mt++)
            acc1[mt] = *(const f32x4*)&sA1[i_loc][mt * 16 + lq * 4];
        // cross features
        const half8v c0 = s0 * dstf0;
        const half8v c1 = s1 * dstf1;
        // GEMM1 (weights from AGPR)
        #pragma unroll
        for (int mt = 0; mt < 8; mt++) {
            mfma_aw(acc1[mt], w1f[mt][0], c0);
            mfma_aw(acc1[mt], w1f[mt][1], c1);
        }
        // epilogue: +B1 (from LDS), relu, pack f16 into P
        unsigned P[16];
        #pragma unroll
        for (int mt = 0; mt < 8; mt++) {
            uint2v bl = *(const uint2v*)&sB1[jl][mt * 16 + lq * 4];
            half2v p0 = cvt_pk(acc1[mt][0], acc1[mt][1]) + __builtin_bit_cast(half2v, bl[0]);
            half2v p1 = cvt_pk(acc1[mt][2], acc1[mt][3]) + __builtin_bit_cast(half2v, bl[1]);
            P[mt * 2 + 0] = __builtin_bit_cast(unsigned, pkmax0(p0));
            P[mt * 2 + 1] = __builtin_bit_cast(unsigned, pkmax0(p1));
        }
        // GEMM2: sigma-W2 (AGPR); B-frag = own P regs; C-init = b2 (from LDS)
        f32x4 acc2[4];
        {
            uint4 hb = {P[0], P[1], P[2], P[3]};
            half8v hf = __builtin_bit_cast(half8v, hb);
            #pragma unroll
            for (int mt2 = 0; mt2 < 4; mt2++) {
                acc2[mt2] = *(const f32x4*)&sB2[mt2 * 16 + lq * 4];
                mfma_aw(acc2[mt2], w2f[mt2][0], hf);
            }
        }
        #pragma unroll
        for (int kt = 1; kt < 4; kt++) {
            uint4 hb = {P[4 * kt], P[4 * kt + 1], P[4 * kt + 2], P[4 * kt + 3]};
            half8v hf = __builtin_bit_cast(half8v, hb);
            #pragma unroll
            for (int mt2 = 0; mt2 < 4; mt2++)
                mfma_aw(acc2[mt2], w2f[mt2][kt], hf);
        }
        // GEMM3 on VALU: part = relu(h2) . w3 (w3 from LDS), reduce over lq
        float part = 0.0f;
        #pragma unroll
        for (int mt2 = 0; mt2 < 4; mt2++) {
            f32x4 w3t = *(const f32x4*)&sW3[mt2 * 16 + lq * 4];
            #pragma unroll
            for (int r = 0; r < 4; r++)
                part += fmaxf(acc2[mt2][r], 0.0f) * w3t[r];
        }
        part += __shfl_xor(part, 16);
        part += __shfl_xor(part, 32);
        if (lane < 16)
            out[(size_t)i * 1024 + jbase + lane] = part + b3s;
    }
}

// ---------------------------------------------------------------------------
extern "C" void kernel_launch(void* const* d_in, const int* in_sizes, int n_in,
                              void* d_out, int out_size, void* d_ws, size_t ws_size,
                              hipStream_t stream) {
    (void)in_sizes; (void)n_in; (void)out_size; (void)ws_size;
    const float* node   = (const float*)d_in[0];
    const float* w_src  = (const float*)d_in[1];
    const float* b_src  = (const float*)d_in[2];
    const float* g_src  = (const float*)d_in[3];
    const float* be_src = (const float*)d_in[4];
    const float* w_dst  = (const float*)d_in[5];
    const float* b_dst  = (const float*)d_in[6];
    const float* g_dst  = (const float*)d_in[7];
    const float* be_dst = (const float*)d_in[8];
    const float* w1     = (const float*)d_in[9];
    const float* b1     = (const float*)d_in[10];
    const float* w2     = (const float*)d_in[11];
    const float* b2     = (const float*)d_in[12];
    const float* w3     = (const float*)d_in[13];
    const float* b3     = (const float*)d_in[14];

    char* ws = (char*)d_ws;
    unsigned short* src_f16  = (unsigned short*)(ws);
    unsigned short* dst_f16  = (unsigned short*)(ws + 131072);
    float*          A1       = (float*)(ws + 262144);
    unsigned short* B1h      = (unsigned short*)(ws + 786432);
    unsigned short* w1c_frag = (unsigned short*)(ws + 1310720);
    unsigned short* w2_frag  = (unsigned short*)(ws + 1327104);

    hipLaunchKernelGGL(proj_kernel, dim3(512), dim3(256), 0, stream,
                       node, w_src, b_src, g_src, be_src, w_dst, b_dst, g_dst, be_dst,
                       w1, b1, w2, src_f16, dst_f16, A1, B1h,
                       w1c_frag, w2_frag);
    hipLaunchKernelGGL(pair_kernel, dim3(32, 32), dim3(256), 0, stream,
                       src_f16, dst_f16, A1, B1h, w1c_frag, w2_frag, b2, w3, b3,
                       (float*)d_out);
}

// Round 12
// 45.398 us; speedup vs baseline: 1.0262x; 1.0262x over previous
//
#include <hip/hip_runtime.h>

typedef _Float16 half2v __attribute__((ext_vector_type(2)));
typedef _Float16 half8v __attribute__((ext_vector_type(8)));
typedef float f32x4 __attribute__((ext_vector_type(4)));
typedef unsigned uint2v __attribute__((ext_vector_type(2)));
typedef unsigned uint4v __attribute__((ext_vector_type(4)));

__device__ inline half2v cvt_pk(float a, float b) {
    return __builtin_bit_cast(half2v, __builtin_amdgcn_cvt_pkrtz(a, b));
}
__device__ inline half2v pkmax0(half2v x) {
    half2v r;
    asm("v_pk_max_f16 %0, %1, 0" : "=v"(r) : "v"(x));
    return r;
}
__device__ inline unsigned short f16bits(float f) {
    _Float16 h = (_Float16)f;
    return __builtin_bit_cast(unsigned short, h);
}
__device__ inline unsigned packf16(float a, float b) {
    return (unsigned)f16bits(a) | ((unsigned)f16bits(b) << 16);
}
__device__ inline float lo16(unsigned u) {
    return (float)__builtin_bit_cast(_Float16, (unsigned short)(u & 0xffffu));
}
__device__ inline float hi16(unsigned u) {
    return (float)__builtin_bit_cast(_Float16, (unsigned short)(u >> 16));
}
// Weights as MFMA A-operand in the AGPR class (separate from the VGPR
// pressure heuristic). R11 showed this is perf-neutral vs spilling, but it
// frees VGPR budget for this round's unroll+hoist.
__device__ inline void mfma_aw(f32x4& c, half8v a, half8v b) {
    uint4v ai = __builtin_bit_cast(uint4v, a);
    uint4v bi = __builtin_bit_cast(uint4v, b);
    asm("v_mfma_f32_16x16x32_f16 %0, %1, %2, %0"
        : "+v"(c) : "a"(ai), "v"(bi));
}

// ---------------------------------------------------------------------------
// K0: src/dst = relu(LN(node @ W^T + b)) -> f16; A1 = src@W1a^T + b1 (f32);
//     B1h = dst@W1b^T (f16). W and the w1 k-slice staged in LDS as f16 with
//     conflict-free strides. Blocks 0..7 pack w1c/w2 into MFMA A-frag order
//     (w2 with sigma perm).
//       sigma(kt, lq*8+e) = (2*kt + (e>>2))*16 + lq*4 + (e&3)
// ---------------------------------------------------------------------------
__global__ __launch_bounds__(256) void proj_kernel(
    const float* __restrict__ node,
    const float* __restrict__ w_src, const float* __restrict__ b_src,
    const float* __restrict__ g_src, const float* __restrict__ be_src,
    const float* __restrict__ w_dst, const float* __restrict__ b_dst,
    const float* __restrict__ g_dst, const float* __restrict__ be_dst,
    const float* __restrict__ w1, const float* __restrict__ b1,
    const float* __restrict__ w2,
    unsigned short* __restrict__ src_f16, unsigned short* __restrict__ dst_f16,
    float* __restrict__ A1, unsigned short* __restrict__ B1h,
    unsigned short* __restrict__ w1c_frag, unsigned short* __restrict__ w2_frag)
{
    __shared__ unsigned sWh[64 * 65];    // W(kind) as packed f16 pairs, stride 65
    __shared__ unsigned sw1h[128 * 33];  // w1[:,koff:koff+64] f16 pairs, stride 33
    __shared__ float snode[4][128];
    __shared__ float sy[4][64];

    const int tid = threadIdx.x;
    const int wloc = tid >> 6;
    const int lane = tid & 63;
    const int gw = blockIdx.x * 4 + wloc;     // 0..2047
    const int row = gw & 1023;
    const int kind = gw >> 10;                // uniform per block

    const float* W  = kind ? w_dst  : w_src;
    const float* Bv = kind ? b_dst  : b_src;
    const float* G  = kind ? g_dst  : g_src;
    const float* BE = kind ? be_dst : be_src;
    const int koff = kind * 64;

    // ---- stage W (64x128) and w1-slice (128x64) as f16 pairs, coalesced ----
    #pragma unroll
    for (int u = 0; u < 16; u++) {
        int w = u * 256 + tid;                // 0..4095
        int r = w >> 6, c2 = w & 63;
        float2 v = *(const float2*)(W + r * 128 + c2 * 2);
        sWh[r * 65 + c2] = packf16(v.x, v.y);
    }
    #pragma unroll
    for (int u = 0; u < 16; u++) {
        int w = u * 256 + tid;                // 0..4095
        int r = w >> 5, c2 = w & 31;
        float2 v = *(const float2*)(w1 + (size_t)r * 192 + koff + c2 * 2);
        sw1h[r * 33 + c2] = packf16(v.x, v.y);
    }
    snode[wloc][lane]      = node[row * 128 + lane];
    snode[wloc][lane + 64] = node[row * 128 + 64 + lane];
    __syncthreads();

    // ---- projection dot: acc = b + node . W[lane,:] ----
    float acc = Bv[lane];
    #pragma unroll 8
    for (int k2 = 0; k2 < 64; k2++) {
        unsigned wp = sWh[lane * 65 + k2];
        float2 nv = *(const float2*)&snode[wloc][2 * k2];
        acc += nv.x * lo16(wp) + nv.y * hi16(wp);
    }

    // LayerNorm over 64 lanes
    float s = acc;
    #pragma unroll
    for (int off = 32; off >= 1; off >>= 1) s += __shfl_xor(s, off);
    float mean = s * (1.0f / 64.0f);
    float d = acc - mean;
    float ss = d * d;
    #pragma unroll
    for (int off = 32; off >= 1; off >>= 1) ss += __shfl_xor(ss, off);
    float rstd = rsqrtf(ss * (1.0f / 64.0f) + 1e-5f);
    float y = fmaxf(d * rstd * G[lane] + BE[lane], 0.0f);

    unsigned short* obf = kind ? dst_f16 : src_f16;
    obf[row * 64 + lane] = f16bits(y);

    sy[wloc][lane] = y;
    __builtin_amdgcn_s_waitcnt(0);   // within-wave LDS RAW

    // ---- A1/B1 projection: a{0,1} = y . w1[m, koff:koff+64] ----
    float a0 = kind ? 0.0f : b1[lane];
    float a1 = kind ? 0.0f : b1[lane + 64];
    #pragma unroll 8
    for (int k2 = 0; k2 < 32; k2++) {
        float2 yv = *(const float2*)&sy[wloc][2 * k2];
        unsigned wa = sw1h[lane * 33 + k2];
        unsigned wb = sw1h[(lane + 64) * 33 + k2];
        a0 += yv.x * lo16(wa) + yv.y * hi16(wa);
        a1 += yv.x * lo16(wb) + yv.y * hi16(wb);
    }
    if (kind == 0) {
        A1[row * 128 + lane] = a0;
        A1[row * 128 + lane + 64] = a1;
    } else {
        B1h[row * 128 + lane] = f16bits(a0);
        B1h[row * 128 + lane + 64] = f16bits(a1);
    }

    // ---- weight packing (blocks 0..7 only) ----
    if (blockIdx.x < 8) {
        int t = blockIdx.x * 256 + threadIdx.x;   // 0..2047
        int which = t >> 10;
        int idx = t & 1023;                       // f*64 + l
        int f = idx >> 6, l = idx & 63;
        int lqq = l >> 4, lrr = l & 15;
        if (which == 0) {
            int mt = f >> 1, kt = f & 1;          // A-frag of W1c
            #pragma unroll
            for (int e = 0; e < 8; e++)
                w1c_frag[idx * 8 + e] =
                    f16bits(w1[(size_t)(mt * 16 + lrr) * 192 + 128 + kt * 32 + lqq * 8 + e]);
        } else {
            int mt2 = f >> 2, kt2 = f & 3;        // A-frag of W2 with sigma perm
            #pragma unroll
            for (int e = 0; e < 8; e++) {
                int col = (2 * kt2 + (e >> 2)) * 16 + lqq * 4 + (e & 3);
                w2_frag[idx * 8 + e] =
                    f16bits(w2[(size_t)(mt2 * 16 + lrr) * 128 + col]);
            }
        }
    }
}

// ---------------------------------------------------------------------------
// K1: pairwise MLP. R12: chunk loop unrolled x4 (compile-time LDS offsets,
// cross-chunk overlap) + j-invariant b1pk hoisted to registers. Weights via
// AGPR asm MFMA. i-side operands in LDS (sA1/sSrc); sB2/sW3 stay in LDS.
// Block = 32 i x 32 j, 4 waves; wave (wv&1, wv>>1) owns 16 i x 16 j.
// ---------------------------------------------------------------------------
__global__ __launch_bounds__(256, 2) void pair_kernel(
    const unsigned short* __restrict__ src_f16, const unsigned short* __restrict__ dst_f16,
    const float* __restrict__ A1, const unsigned short* __restrict__ B1h,
    const unsigned short* __restrict__ w1c_frag, const unsigned short* __restrict__ w2_frag,
    const float* __restrict__ b2, const float* __restrict__ w3,
    const float* __restrict__ b3, float* __restrict__ out)
{
    __shared__ __align__(16) float sA1[32][128];           // 16 KB
    __shared__ __align__(16) unsigned short sSrc[32][64];  // 4 KB
    __shared__ __align__(16) float sB2[128];               // 0.5 KB
    __shared__ __align__(16) float sW3[64];                // 0.25 KB

    const int tid = threadIdx.x;
    const int wv = tid >> 6;
    const int lane = tid & 63;
    const int lq = lane >> 4, lr = lane & 15;
    const int i0 = blockIdx.y * 32, j0 = blockIdx.x * 32;
    const int ibase = (wv & 1) * 16;
    const int jl_base = (wv >> 1) * 16;
    const int jbase = j0 + jl_base;

    // ---- cooperative staging (coalesced) ----
    #pragma unroll
    for (int u = 0; u < 4; u++) {
        int idx = u * 256 + tid;              // 0..1023
        int r = idx >> 5, c = (idx & 31) * 4;
        *(f32x4*)&sA1[r][c] = *(const f32x4*)(A1 + (size_t)(i0 + r) * 128 + c);
    }
    {
        int r = tid >> 3, c = (tid & 7) * 8;
        *(uint4*)&sSrc[r][c] = *(const uint4*)(src_f16 + (size_t)(i0 + r) * 64 + c);
    }
    if (tid < 32) *(f32x4*)&sB2[tid * 4] = *(const f32x4*)(b2 + tid * 4);
    else if (tid < 48) *(f32x4*)&sW3[(tid - 32) * 4] = *(const f32x4*)(w3 + (tid - 32) * 4);

    // ---- weight fragments from global (coalesced b128, L2-hot) ----
    half8v w1f[8][2], w2f[4][4];
    {
        const uint4* gw1 = (const uint4*)w1c_frag;
        #pragma unroll
        for (int mt = 0; mt < 8; mt++)
            #pragma unroll
            for (int kt = 0; kt < 2; kt++)
                w1f[mt][kt] = __builtin_bit_cast(half8v, gw1[(mt * 2 + kt) * 64 + lane]);
        const uint4* gw2 = (const uint4*)w2_frag;
        #pragma unroll
        for (int mt2 = 0; mt2 < 4; mt2++)
            #pragma unroll
            for (int kt = 0; kt < 4; kt++)
                w2f[mt2][kt] = __builtin_bit_cast(half8v, gw2[(mt2 * 4 + kt) * 64 + lane]);
    }
    const float b3s = b3[0];

    // ---- j-side package: loaded once per wave, register-resident ----
    const int j = jbase + lr;
    half8v dstf0, dstf1;
    {
        const uint4* drow = (const uint4*)(dst_f16 + (size_t)j * 64);
        dstf0 = __builtin_bit_cast(half8v, drow[lq]);
        dstf1 = __builtin_bit_cast(half8v, drow[4 + lq]);
    }
    half2v b1pk[8][2];
    #pragma unroll
    for (int mt = 0; mt < 8; mt++) {
        uint2v bl = *(const uint2v*)(B1h + (size_t)j * 128 + mt * 16 + lq * 4);
        b1pk[mt][0] = __builtin_bit_cast(half2v, bl[0]);
        b1pk[mt][1] = __builtin_bit_cast(half2v, bl[1]);
    }

    __syncthreads();

    // ---- 16 chunks, unrolled x4: compile-time LDS offsets, cross-chunk ILP ----
    #pragma unroll 4
    for (int cc = 0; cc < 16; cc++) {
        const int i_loc = ibase + cc;
        const int i = i0 + i_loc;
        const half8v s0 = *(const half8v*)&sSrc[i_loc][lq * 8];
        const half8v s1 = *(const half8v*)&sSrc[i_loc][32 + lq * 8];
        f32x4 acc1[8];
        #pragma unroll
        for (int mt = 0; mt < 8; mt++)
            acc1[mt] = *(const f32x4*)&sA1[i_loc][mt * 16 + lq * 4];
        // cross features
        const half8v c0 = s0 * dstf0;
        const half8v c1 = s1 * dstf1;
        // GEMM1 (weights from AGPR)
        #pragma unroll
        for (int mt = 0; mt < 8; mt++) {
            mfma_aw(acc1[mt], w1f[mt][0], c0);
            mfma_aw(acc1[mt], w1f[mt][1], c1);
        }
        // epilogue: +B1 (regs), relu, pack f16 into P
        unsigned P[16];
        #pragma unroll
        for (int mt = 0; mt < 8; mt++) {
            half2v p0 = cvt_pk(acc1[mt][0], acc1[mt][1]) + b1pk[mt][0];
            half2v p1 = cvt_pk(acc1[mt][2], acc1[mt][3]) + b1pk[mt][1];
            P[mt * 2 + 0] = __builtin_bit_cast(unsigned, pkmax0(p0));
            P[mt * 2 + 1] = __builtin_bit_cast(unsigned, pkmax0(p1));
        }
        // GEMM2: sigma-W2 (AGPR); B-frag = own P regs; C-init = b2 (LDS)
        f32x4 acc2[4];
        {
            uint4 hb = {P[0], P[1], P[2], P[3]};
            half8v hf = __builtin_bit_cast(half8v, hb);
            #pragma unroll
            for (int mt2 = 0; mt2 < 4; mt2++) {
                acc2[mt2] = *(const f32x4*)&sB2[mt2 * 16 + lq * 4];
                mfma_aw(acc2[mt2], w2f[mt2][0], hf);
            }
        }
        #pragma unroll
        for (int kt = 1; kt < 4; kt++) {
            uint4 hb = {P[4 * kt], P[4 * kt + 1], P[4 * kt + 2], P[4 * kt + 3]};
            half8v hf = __builtin_bit_cast(half8v, hb);
            #pragma unroll
            for (int mt2 = 0; mt2 < 4; mt2++)
                mfma_aw(acc2[mt2], w2f[mt2][kt], hf);
        }
        // GEMM3 on VALU: part = relu(h2) . w3 (LDS), reduce over lq
        float part = 0.0f;
        #pragma unroll
        for (int mt2 = 0; mt2 < 4; mt2++) {
            f32x4 w3t = *(const f32x4*)&sW3[mt2 * 16 + lq * 4];
            #pragma unroll
            for (int r = 0; r < 4; r++)
                part += fmaxf(acc2[mt2][r], 0.0f) * w3t[r];
        }
        part += __shfl_xor(part, 16);
        part += __shfl_xor(part, 32);
        if (lane < 16)
            out[(size_t)i * 1024 + jbase + lane] = part + b3s;
    }
}

// ---------------------------------------------------------------------------
extern "C" void kernel_launch(void* const* d_in, const int* in_sizes, int n_in,
                              void* d_out, int out_size, void* d_ws, size_t ws_size,
                              hipStream_t stream) {
    (void)in_sizes; (void)n_in; (void)out_size; (void)ws_size;
    const float* node   = (const float*)d_in[0];
    const float* w_src  = (const float*)d_in[1];
    const float* b_src  = (const float*)d_in[2];
    const float* g_src  = (const float*)d_in[3];
    const float* be_src = (const float*)d_in[4];
    const float* w_dst  = (const float*)d_in[5];
    const float* b_dst  = (const float*)d_in[6];
    const float* g_dst  = (const float*)d_in[7];
    const float* be_dst = (const float*)d_in[8];
    const float* w1     = (const float*)d_in[9];
    const float* b1     = (const float*)d_in[10];
    const float* w2     = (const float*)d_in[11];
    const float* b2     = (const float*)d_in[12];
    const float* w3     = (const float*)d_in[13];
    const float* b3     = (const float*)d_in[14];

    char* ws = (char*)d_ws;
    unsigned short* src_f16  = (unsigned short*)(ws);
    unsigned short* dst_f16  = (unsigned short*)(ws + 131072);
    float*          A1       = (float*)(ws + 262144);
    unsigned short* B1h      = (unsigned short*)(ws + 786432);
    unsigned short* w1c_frag = (unsigned short*)(ws + 1310720);
    unsigned short* w2_frag  = (unsigned short*)(ws + 1327104);

    hipLaunchKernelGGL(proj_kernel, dim3(512), dim3(256), 0, stream,
                       node, w_src, b_src, g_src, be_src, w_dst, b_dst, g_dst, be_dst,
                       w1, b1, w2, src_f16, dst_f16, A1, B1h,
                       w1c_frag, w2_frag);
    hipLaunchKernelGGL(pair_kernel, dim3(32, 32), dim3(256), 0, stream,
                       src_f16, dst_f16, A1, B1h, w1c_frag, w2_frag, b2, w3, b3,
                       (float*)d_out);
}